// Round 4
// baseline (614.985 us; speedup 1.0000x reference)
//
#include <hip/hip_runtime.h>

// JKNet (6-layer GCN + JK concat) on MI355X — R11:
//   * REVERT R10 fusion (it cut agg occupancy 30% and regressed).
//   * g stored as 3 feature planes [p][n][32] bf16 (64B/row = 1 cache line;
//     3.2MB/plane < 4MB per-XCD L2). agg processes plane-by-plane with the
//     plane loop outermost + grid <= resident capacity, so the instantaneous
//     gather working set is L2-resident (R10 counters: FETCH 102MB on a 9.6MB
//     buffer = L2 thrash at 1.4TB/s was the bottleneck).
//   * full-wave gather: 8 lanes/edge x 8 edges per load instruction; col
//     indices preloaded once per row and register-cached across planes.
// Layout facts (learn_hip m89): A[m=lane&15][k=quad*8+j], B[k][n=lane&15] (k=quad*8+j),
// D: col=lane&15, row=quad*4+reg.

typedef unsigned short ushortT;
typedef __attribute__((ext_vector_type(8))) short bf16x8;
typedef __attribute__((ext_vector_type(4))) float f32x4;

__device__ __forceinline__ ushortT f2b(float f) {
    union { float f; unsigned int u; } v;
    v.f = f;
    unsigned int lsb = (v.u >> 16) & 1u;
    v.u += 0x7fffu + lsb;  // RNE
    return (ushortT)(v.u >> 16);
}
__device__ __forceinline__ float b2f(ushortT u) {
    union { float f; unsigned int u; } v;
    v.u = ((unsigned int)u) << 16;
    return v.f;
}

// ---- fused prep: transpose+convert all weights, zero degi -----------------
__global__ void prep_kernel(const float* __restrict__ W1, const float* __restrict__ Wsl,
                            const float* __restrict__ Wout, ushortT* __restrict__ wt1,
                            ushortT* __restrict__ wts, ushortT* __restrict__ wto,
                            int* __restrict__ degi, int n) {
    const int SQ = 96 * 96;        // 9216
    const int T1 = 5 * SQ;         // 46080
    const int T2 = T1 + 480 * 64;  // 76800
    int i = blockIdx.x * blockDim.x + threadIdx.x;
    if (i < T1) {
        int l = i / SQ, j = i - l * SQ;
        int c = j / 96, k = j - c * 96;
        if (l == 0)
            wt1[j] = f2b(W1[k * 96 + c]);
        else
            wts[(size_t)(l - 1) * SQ + j] = f2b(Wsl[(size_t)(l - 1) * SQ + k * 96 + c]);
    } else if (i < T2) {
        int j = i - T1;
        int c = j / 480, k = j - c * 480;
        wto[j] = f2b(Wout[(size_t)k * 64 + c]);
    } else {
        int j = i - T2;
        if (j < n) degi[j] = 0;
    }
}

// ---- CSR build -------------------------------------------------------------
__global__ void count_kernel(const int* __restrict__ dst, int* __restrict__ degi, int E) {
    int e = blockIdx.x * blockDim.x + threadIdx.x;
    if (e < E) atomicAdd(&degi[dst[e]], 1);
}

__global__ void scan1(const int* __restrict__ degi, int* __restrict__ row_start,
                      int* __restrict__ partials, int n) {
    __shared__ int tmp[256];
    const int t = threadIdx.x;
    const int i = blockIdx.x * 256 + t;
    int val = (i < n) ? degi[i] : 0;
    tmp[t] = val;
    __syncthreads();
    for (int off = 1; off < 256; off <<= 1) {
        int v = (t >= off) ? tmp[t - off] : 0;
        __syncthreads();
        tmp[t] += v;
        __syncthreads();
    }
    if (i < n) row_start[i] = tmp[t] - val;
    if (t == 255) partials[blockIdx.x] = tmp[255];
}

__global__ void scan2(int* __restrict__ partials, int nb) {
    __shared__ int tmp[256];
    const int t = threadIdx.x;
    int val = (t < nb) ? partials[t] : 0;
    tmp[t] = val;
    __syncthreads();
    for (int off = 1; off < 256; off <<= 1) {
        int v = (t >= off) ? tmp[t - off] : 0;
        __syncthreads();
        tmp[t] += v;
        __syncthreads();
    }
    if (t < nb) partials[t] = tmp[t] - val;
}

__global__ void scan3(const int* __restrict__ degi, int* __restrict__ row_start,
                      const int* __restrict__ partials, float* __restrict__ dinv,
                      int n, int E) {
    const int i = blockIdx.x * 256 + threadIdx.x;
    if (i < n) {
        row_start[i] += partials[blockIdx.x];
        dinv[i] = rsqrtf((float)degi[i] + 1.0f);
    }
    if (i == 0) row_start[n] = E;
}

__global__ void fill_kernel(const int* __restrict__ src, const int* __restrict__ dst,
                            const int* __restrict__ row_start, int* __restrict__ degi,
                            int* __restrict__ col, int E) {
    int e = blockIdx.x * blockDim.x + threadIdx.x;
    if (e < E) {
        int d = dst[e];
        int pos = row_start[d] + atomicSub(&degi[d], 1) - 1;
        col[pos] = src[e];
    }
}

// ---- MFMA GEMM [n,96]x[96,96] -> g planes = (X@W)*dinv[row] ----------------
// g layout: 3 planes, plane p at g + p*n*32, row-major [n][32] bf16.
template <typename TIN>
__global__ __launch_bounds__(256) void gemm96_mfma(const TIN* __restrict__ X,
                                                   const ushortT* __restrict__ Wt, // [96][96] c-major
                                                   const float* __restrict__ dinv,
                                                   ushortT* __restrict__ g, int n) {
    __shared__ __attribute__((aligned(16))) ushortT Xl[64][104];
    __shared__ __attribute__((aligned(16))) ushortT Wtl[96][104];
    const int tid = threadIdx.x;
    const int wave = tid >> 6, lane = tid & 63;
    const int quad = lane >> 4, m = lane & 15;
    const int row_base = blockIdx.x * 64;
    const size_t pstride = (size_t)n * 32;
    for (int i = tid; i < 96 * 24; i += 256) {
        int r = i / 24, c4 = (i % 24) * 4;
        *(ushort4*)&Wtl[r][c4] = *(const ushort4*)&Wt[r * 96 + c4];
    }
    for (int i = tid; i < 64 * 24; i += 256) {
        int r = i / 24, c4 = (i % 24) * 4;
        int grow = min(row_base + r, n - 1);
        if constexpr (sizeof(TIN) == 4) {
            float4 v = *(const float4*)&X[(size_t)grow * 96 + c4];
            ushort4 o = {f2b(v.x), f2b(v.y), f2b(v.z), f2b(v.w)};
            *(ushort4*)&Xl[r][c4] = o;
        } else {
            *(ushort4*)&Xl[r][c4] = *(const ushort4*)&X[(size_t)grow * 96 + c4];
        }
    }
    __syncthreads();
    f32x4 acc[6] = {};
#pragma unroll
    for (int ks = 0; ks < 3; ++ks) {
        bf16x8 a = *(bf16x8*)&Xl[wave * 16 + m][ks * 32 + quad * 8];
#pragma unroll
        for (int ct = 0; ct < 6; ++ct) {
            bf16x8 b = *(bf16x8*)&Wtl[ct * 16 + m][ks * 32 + quad * 8];
            acc[ct] = __builtin_amdgcn_mfma_f32_16x16x32_bf16(a, b, acc[ct], 0, 0, 0);
        }
    }
    float di[4];
    int rows[4];
#pragma unroll
    for (int r = 0; r < 4; ++r) {
        rows[r] = row_base + wave * 16 + quad * 4 + r;
        di[r] = (rows[r] < n) ? dinv[rows[r]] : 0.f;
    }
#pragma unroll
    for (int ct = 0; ct < 6; ++ct) {
        const int plane = ct >> 1;
        const int pcol = (ct & 1) * 16 + m;
#pragma unroll
        for (int r = 0; r < 4; ++r)
            if (rows[r] < n)
                g[(size_t)plane * pstride + (size_t)rows[r] * 32 + pcol] =
                    f2b(acc[ct][r] * di[r]);
    }
}

// ---- MFMA GEMM [n,480]x[480,64] -> g (2 planes). K = 5 JK segs x 96. -------
template <typename TIN>
__global__ __launch_bounds__(256) void gemm_out_mfma(const TIN* __restrict__ hcat,
                                                     const ushortT* __restrict__ Wt, // [64][480]
                                                     const float* __restrict__ dinv,
                                                     ushortT* __restrict__ g, int n) {
    __shared__ __attribute__((aligned(16))) ushortT Xl[64][104];
    __shared__ __attribute__((aligned(16))) ushortT Wtl[64][104];
    const int tid = threadIdx.x;
    const int wave = tid >> 6, lane = tid & 63;
    const int quad = lane >> 4, m = lane & 15;
    const int row_base = blockIdx.x * 64;
    const size_t pstride = (size_t)n * 32;
    f32x4 acc[4] = {};
    for (int seg = 0; seg < 5; ++seg) {
        const TIN* hl = hcat + (size_t)seg * (size_t)n * 96;
        __syncthreads();
        for (int i = tid; i < 64 * 24; i += 256) {
            int r = i / 24, c4 = (i % 24) * 4;
            *(ushort4*)&Wtl[r][c4] = *(const ushort4*)&Wt[r * 480 + seg * 96 + c4];
        }
        for (int i = tid; i < 64 * 24; i += 256) {
            int r = i / 24, c4 = (i % 24) * 4;
            int grow = min(row_base + r, n - 1);
            if constexpr (sizeof(TIN) == 4) {
                float4 v = *(const float4*)&hl[(size_t)grow * 96 + c4];
                ushort4 o = {f2b(v.x), f2b(v.y), f2b(v.z), f2b(v.w)};
                *(ushort4*)&Xl[r][c4] = o;
            } else {
                *(ushort4*)&Xl[r][c4] = *(const ushort4*)&hl[(size_t)grow * 96 + c4];
            }
        }
        __syncthreads();
#pragma unroll
        for (int ks = 0; ks < 3; ++ks) {
            bf16x8 a = *(bf16x8*)&Xl[wave * 16 + m][ks * 32 + quad * 8];
#pragma unroll
            for (int ct = 0; ct < 4; ++ct) {
                bf16x8 b = *(bf16x8*)&Wtl[ct * 16 + m][ks * 32 + quad * 8];
                acc[ct] = __builtin_amdgcn_mfma_f32_16x16x32_bf16(a, b, acc[ct], 0, 0, 0);
            }
        }
    }
    float di[4];
    int rows[4];
#pragma unroll
    for (int r = 0; r < 4; ++r) {
        rows[r] = row_base + wave * 16 + quad * 4 + r;
        di[r] = (rows[r] < n) ? dinv[rows[r]] : 0.f;
    }
#pragma unroll
    for (int ct = 0; ct < 4; ++ct) {
        const int plane = ct >> 1;
        const int pcol = (ct & 1) * 16 + m;
#pragma unroll
        for (int r = 0; r < 4; ++r)
            if (rows[r] < n)
                g[(size_t)plane * pstride + (size_t)rows[r] * 32 + pcol] =
                    f2b(acc[ct][r] * di[r]);
    }
}

// ---- plane-blocked CSR aggregate -------------------------------------------
// g = NPLANES planes of [n][32] bf16 (64B rows). Plane loop OUTERMOST: the
// instantaneous gather working set is one 3.2MB plane (fits 4MB per-XCD L2).
// Grid sized <= resident capacity so all blocks start together and stay
// phase-aligned. Full wave per row: 8 lanes/edge x 8 edges per gather
// instruction; col indices preloaded once per row, register-cached across
// planes, broadcast with one __shfl per 8 edges.
template <int NPLANES, int HW, bool RELU, bool WRITE_BF16>
__global__ __launch_bounds__(256, 8) void agg_planes(
        const int* __restrict__ row_start, const int* __restrict__ col,
        const ushortT* __restrict__ g, const float* __restrict__ dinv,
        const float* __restrict__ bias, float* __restrict__ out,
        ushortT* __restrict__ hb, int n) {
    constexpr int RPW = 7;  // rows per wave
    const int lane = threadIdx.x & 63;
    const int f8 = lane & 7;
    const int eslot = lane >> 3;
    const int gw = blockIdx.x * (blockDim.x >> 6) + (threadIdx.x >> 6);
    const int r0 = gw * RPW;
    const size_t pstride = (size_t)n * 32;

    int e0a[RPW], dga[RPW], cva[RPW];
    float dva[RPW];
#pragma unroll
    for (int i = 0; i < RPW; ++i) {
        const int row = r0 + i;
        e0a[i] = 0; dga[i] = 0; dva[i] = 0.f; cva[i] = 0;
        if (row < n) {
            const int e0 = row_start[row];
            const int e1 = row_start[row + 1];
            e0a[i] = e0;
            dga[i] = e1 - e0;
            dva[i] = dinv[row];
            if (lane < min(e1 - e0, 64)) cva[i] = col[e0 + lane];
        }
    }

#pragma unroll
    for (int p = 0; p < NPLANES; ++p) {
        const ushortT* gp = g + (size_t)p * pstride;
        const float4 bv = *(const float4*)&bias[p * 32 + f8 * 4];
#pragma unroll
        for (int i = 0; i < RPW; ++i) {
            const int row = r0 + i;
            if (row < n) {
                const int deg = dga[i];
                float a0 = 0.f, a1 = 0.f, a2 = 0.f, a3 = 0.f;
                if (eslot == 0) {  // self loop
                    ushort4 s = *(const ushort4*)&gp[(size_t)row * 32 + f8 * 4];
                    a0 = b2f(s.x); a1 = b2f(s.y); a2 = b2f(s.z); a3 = b2f(s.w);
                }
                const int kc = min(deg, 64);
                const int rounds = (kc + 7) >> 3;
                for (int r = 0; r < rounds; ++r) {
                    const int idx = (r << 3) + eslot;
                    const int c = __shfl(cva[i], idx);
                    if (idx < kc) {
                        ushort4 gg = *(const ushort4*)&gp[(size_t)c * 32 + f8 * 4];
                        a0 += b2f(gg.x); a1 += b2f(gg.y);
                        a2 += b2f(gg.z); a3 += b2f(gg.w);
                    }
                }
                if (deg > 64) {  // rare (Poisson(16) tail)
                    for (int done = 64; done < deg; done += 64) {
                        const int kc2 = min(deg - done, 64);
                        int cv2 = 0;
                        if (lane < kc2) cv2 = col[e0a[i] + done + lane];
                        const int rr = (kc2 + 7) >> 3;
                        for (int r = 0; r < rr; ++r) {
                            const int idx = (r << 3) + eslot;
                            const int c = __shfl(cv2, idx);
                            if (idx < kc2) {
                                ushort4 gg = *(const ushort4*)&gp[(size_t)c * 32 + f8 * 4];
                                a0 += b2f(gg.x); a1 += b2f(gg.y);
                                a2 += b2f(gg.z); a3 += b2f(gg.w);
                            }
                        }
                    }
                }
                a0 += __shfl_xor(a0, 8); a0 += __shfl_xor(a0, 16); a0 += __shfl_xor(a0, 32);
                a1 += __shfl_xor(a1, 8); a1 += __shfl_xor(a1, 16); a1 += __shfl_xor(a1, 32);
                a2 += __shfl_xor(a2, 8); a2 += __shfl_xor(a2, 16); a2 += __shfl_xor(a2, 32);
                a3 += __shfl_xor(a3, 8); a3 += __shfl_xor(a3, 16); a3 += __shfl_xor(a3, 32);
                if (lane < 8) {
                    const float di = dva[i];
                    float4 rv;
                    rv.x = a0 * di + bv.x;
                    rv.y = a1 * di + bv.y;
                    rv.z = a2 * di + bv.z;
                    rv.w = a3 * di + bv.w;
                    if (RELU) {
                        rv.x = fmaxf(rv.x, 0.f); rv.y = fmaxf(rv.y, 0.f);
                        rv.z = fmaxf(rv.z, 0.f); rv.w = fmaxf(rv.w, 0.f);
                    }
                    *(float4*)&out[(size_t)row * HW + p * 32 + lane * 4] = rv;
                    if (WRITE_BF16) {
                        ushort4 o = {f2b(rv.x), f2b(rv.y), f2b(rv.z), f2b(rv.w)};
                        *(ushort4*)&hb[(size_t)row * 96 + p * 32 + lane * 4] = o;
                    }
                }
            }
        }
        __syncthreads();  // keep block's waves phase-aligned on the plane
    }
}

extern "C" void kernel_launch(void* const* d_in, const int* in_sizes, int n_in,
                              void* d_out, int out_size, void* d_ws, size_t ws_size,
                              hipStream_t stream) {
    const float* x    = (const float*)d_in[0];
    const int*   ei   = (const int*)d_in[1];
    const float* W1   = (const float*)d_in[4];
    const float* b1   = (const float*)d_in[5];
    const float* Wsl  = (const float*)d_in[6];
    const float* bsl  = (const float*)d_in[7];
    const float* Wout = (const float*)d_in[8];
    const float* bout = (const float*)d_in[9];

    const int n = in_sizes[0] / 96;  // 50000
    const int E = in_sizes[1] / 2;   // 800000
    const int* src = ei;
    const int* dst = ei + E;

    // ws: degi row_start partials col (int) | dinv (f32) | g (bf16 n*96, 3 planes)
    //     | hball (bf16, 5*n*96 or n*96) | wt1 wts wto (bf16)
    char* p = (char*)d_ws;
    int*     degi      = (int*)p;              p += (size_t)n * 4;
    int*     row_start = (int*)p;              p += (size_t)(n + 1) * 4;
    int*     partials  = (int*)p;              p += 256 * 4;
    int*     col       = (int*)p;              p += (size_t)E * 4;
    float*   dinv      = (float*)p;            p += (size_t)n * 4;
    ushortT* g         = (ushortT*)p;          p += (size_t)n * 96 * 2;
    ushortT* hball     = (ushortT*)p;
    const size_t wbytes = (size_t)(5 * 9216 + 30720) * 2;
    const size_t fixed  = (size_t)(p - (char*)d_ws);
    const bool   big    = (fixed + (size_t)5 * n * 96 * 2 + wbytes) <= ws_size;
    const size_t hbsz   = big ? (size_t)5 * n * 96 : (size_t)n * 96;
    p += hbsz * 2;
    ushortT* wt1 = (ushortT*)p;
    ushortT* wts = wt1 + 9216;
    ushortT* wto = wts + 4 * 9216;

    float* out  = (float*)d_out;          // [n,64]
    float* hseg = out + (size_t)n * 64;   // h1 base; 5 segments of n*96 fp32

    const int nthr  = 256;
    const int gE    = (E + nthr - 1) / nthr;
    const int gT64  = (n + 63) / 64;
    const int nb    = (n + 255) / 256;
    const int gAggP = (n + 4 * 7 - 1) / (4 * 7);  // 4 waves/block x 7 rows/wave

    // fused prep: weights + degi zero
    const int prep_items = 76800 + n;
    prep_kernel<<<(prep_items + 255) / 256, 256, 0, stream>>>(W1, Wsl, Wout, wt1, wts,
                                                              wto, degi, n);

    // CSR build
    count_kernel<<<gE, nthr, 0, stream>>>(dst, degi, E);
    scan1<<<nb, 256, 0, stream>>>(degi, row_start, partials, n);
    scan2<<<1, 256, 0, stream>>>(partials, nb);
    scan3<<<nb, 256, 0, stream>>>(degi, row_start, partials, dinv, n, E);
    fill_kernel<<<gE, nthr, 0, stream>>>(src, dst, row_start, degi, col, E);

    // layer 1: x(fp32) -> g planes -> h1 (+hb seg 0)
    gemm96_mfma<float><<<gT64, 256, 0, stream>>>(x, wt1, dinv, g, n);
    agg_planes<3, 96, true, true><<<gAggP, nthr, 0, stream>>>(
        row_start, col, g, dinv, b1, hseg, hball, n);

    // hidden layers 2..5: hb(bf16) -> g planes -> h_{l+1} (+hb seg l+1)
    for (int l = 0; l < 4; ++l) {
        float*   hnext = hseg + (size_t)(l + 1) * (size_t)n * 96;
        ushortT* hbin  = big ? (hball + (size_t)l * n * 96) : hball;
        ushortT* hbout = big ? (hball + (size_t)(l + 1) * n * 96) : hball;
        gemm96_mfma<ushortT><<<gT64, 256, 0, stream>>>(hbin, wts + (size_t)l * 9216,
                                                       dinv, g, n);
        agg_planes<3, 96, true, true><<<gAggP, nthr, 0, stream>>>(
            row_start, col, g, dinv, bsl + (size_t)l * 96, hnext, hbout, n);
    }

    // output layer: JK concat -> g (2 planes) -> out[n,64]
    if (big)
        gemm_out_mfma<ushortT><<<gT64, 256, 0, stream>>>(hball, wto, dinv, g, n);
    else
        gemm_out_mfma<float><<<gT64, 256, 0, stream>>>(hseg, wto, dinv, g, n);
    agg_planes<2, 64, false, false><<<gAggP, nthr, 0, stream>>>(
        row_start, col, g, dinv, bout, out, nullptr, n);
}